// Round 9
// baseline (1367.762 us; speedup 1.0000x reference)
//
#include <hip/hip_runtime.h>
#include <hip/hip_bf16.h>
#include <math.h>

#define N_SIMP 400000
#define E_NNZ  2400000
#define FIN    32
#define HDIM   64
#define KAPPA  3
#define G_NUM  512
#define NOUT   8
#define BN_EPS 1e-5

// ---- CSR build (two-level LDS counting sort; pass-1 sorts fully in LDS) ----
#define NDIG_HALF 391             // ceil(400000/1024) coarse buckets per matrix
#define NDIG      782             // L + U
#define P1_EDGES  8192            // edges per pass-1 block (8/thread @ 1024 thr)
#define P1_BLOCKS 586             // ceil(4.8M / 8192)
#define P1_T      1024
#define P1_EPT    8
#define P2_CAP    7168            // bucket capacity (avg 6144, +13 sigma headroom)
#define P2_T      512
#define P2_ITERS  14              // P2_CAP / P2_T

typedef __hip_bfloat16 bf16;
typedef _Float16 f16;
typedef short s8v __attribute__((ext_vector_type(8)));    // 8 bf16 in 4 VGPRs
typedef ushort u8v __attribute__((ext_vector_type(8)));   // 8 bf16 raw
typedef _Float16 h8v __attribute__((ext_vector_type(8))); // 8 f16
typedef float f4v __attribute__((ext_vector_type(4)));

__device__ __forceinline__ float elu_f(float x) {
    return x > 0.f ? x : expm1f(x);
}
__device__ __forceinline__ float bf2f(ushort u) {
    return __uint_as_float(((unsigned int)u) << 16);
}
__device__ __forceinline__ ushort f2bf(float f) {
    bf16 h = (bf16)f;
    return *(ushort*)&h;
}

// ---------------- CSR build: pass 1 (full in-LDS counting sort per block) -------
// 72.7 KB LDS -> 2 blocks/CU (32 waves) for latency hiding.

__global__ __launch_bounds__(P1_T) void p1_sort_kernel(
        const int* __restrict__ eiL, const float* __restrict__ lv,
        const int* __restrict__ eiU, const float* __restrict__ uv,
        int* __restrict__ ccnt, int* __restrict__ bofsv,
        int2* __restrict__ coarse) {
    __shared__ int2 rec[P1_EDGES];   // 64 KB
    __shared__ int h[NDIG];          // counts -> running offsets
    __shared__ int hscan[P1_T];      // scan scratch
    int t = threadIdx.x;
    for (int j = t; j < NDIG; j += P1_T) h[j] = 0;
    __syncthreads();
    int base_i = blockIdx.x * P1_EDGES;
    int key[P1_EPT], val[P1_EPT], dg[P1_EPT];
#pragma unroll
    for (int k = 0; k < P1_EPT; ++k) {
        int i = base_i + k * P1_T + t;
        int dd = -1;
        if (i < 2 * E_NNZ) {
            int row, col;
            float v;
            if (i < E_NNZ) {
                row = eiL[i]; col = eiL[E_NNZ + i]; v = lv[i];
                dd = row >> 10;
            } else {
                int e = i - E_NNZ;
                row = eiU[e]; col = eiU[E_NNZ + e]; v = uv[e];
                dd = NDIG_HALF + (row >> 10);
            }
            key[k] = ((row & 1023) << 22) | col;
            val[k] = __float_as_int(v);
            atomicAdd(&h[dd], 1);
        }
        dg[k] = dd;
    }
    __syncthreads();
    // scan the 782 counts (1024-thread Hillis-Steele); emit ccnt/bofs; h := excl.
    int cv = (t < NDIG) ? h[t] : 0;
    hscan[t] = cv;
    __syncthreads();
    for (int off = 1; off < P1_T; off <<= 1) {
        int x = (t >= off) ? hscan[t - off] : 0;
        __syncthreads();
        hscan[t] += x;
        __syncthreads();
    }
    if (t < NDIG) {
        int ex = hscan[t] - cv;
        ccnt[blockIdx.x * NDIG + t] = cv;
        bofsv[blockIdx.x * NDIG + t] = ex;
        h[t] = ex;
    }
    __syncthreads();
    // placement into digit-sorted LDS buffer
#pragma unroll
    for (int k = 0; k < P1_EPT; ++k) {
        if (dg[k] >= 0) {
            int pos = atomicAdd(&h[dg[k]], 1);
            rec[pos] = make_int2(key[k], val[k]);
        }
    }
    __syncthreads();
    // contiguous stream-out: full-line writes only
    int2* dst = coarse + (size_t)blockIdx.x * P1_EDGES;
    int nrec = 2 * E_NNZ - base_i;
    if (nrec > P1_EDGES) nrec = P1_EDGES;
    for (int j = t; j < nrec; j += P1_T) dst[j] = rec[j];
}

// per-digit totals over blocks
__global__ void digit_total_kernel(const int* __restrict__ cnt, int* __restrict__ tot) {
    int d = blockIdx.x * 256 + threadIdx.x;
    if (d >= NDIG) return;
    int run = 0;
    for (int b = 0; b < P1_BLOCKS; ++b) run += cnt[b * NDIG + d];
    tot[d] = run;
}

// exclusive scan of tot[NDIG] in place (becomes digit global base)
__global__ __launch_bounds__(1024) void scan_base_kernel(int* __restrict__ tot) {
    __shared__ int s[1024];
    int t = threadIdx.x;
    int v = (t < NDIG) ? tot[t] : 0;
    s[t] = v;
    __syncthreads();
    for (int off = 1; off < 1024; off <<= 1) {
        int x = (t >= off) ? s[t - off] : 0;
        __syncthreads();
        s[t] += x;
        __syncthreads();
    }
    if (t < NDIG) tot[t] = s[t] - v;
    if (t == 1023) tot[NDIG] = s[1023];   // = 2*E_NNZ
}

// ---------------- CSR build: pass 2 (fragment gather + LDS counting sort) -------

__global__ __launch_bounds__(P2_T) void p2_build_kernel(
        const int2* __restrict__ coarse, const int* __restrict__ ccnt,
        const int* __restrict__ bofsv, const int* __restrict__ basev,
        int* __restrict__ rpL, int* __restrict__ rpU,
        int2* __restrict__ edgeL, int2* __restrict__ edgeU) {
    __shared__ int pk[P2_CAP];
    __shared__ int vl[P2_CAP];
    __shared__ int hist[1024];
    __shared__ int sc[P2_T];
    __shared__ int flen[P1_BLOCKS];
    __shared__ int fofs[P1_BLOCKS];
    __shared__ int fo[P1_BLOCKS];
    __shared__ int stot;
    int d = blockIdx.x;
    int t = threadIdx.x;
    // fragment table: 586 fragments; thread t handles fragments 2t, 2t+1 (pair scan)
    int f0 = 2 * t, f1 = 2 * t + 1;
    int L0 = 0, L1 = 0, O0 = 0, O1 = 0;
    if (f0 < P1_BLOCKS) { L0 = ccnt[f0 * NDIG + d]; O0 = bofsv[f0 * NDIG + d]; }
    if (f1 < P1_BLOCKS) { L1 = ccnt[f1 * NDIG + d]; O1 = bofsv[f1 * NDIG + d]; }
    sc[t] = L0 + L1;
    __syncthreads();
    for (int off = 1; off < P2_T; off <<= 1) {
        int x = (t >= off) ? sc[t - off] : 0;
        __syncthreads();
        sc[t] += x;
        __syncthreads();
    }
    int pb = sc[t] - (L0 + L1);
    if (f0 < P1_BLOCKS) { flen[f0] = L0; fofs[f0] = O0; fo[f0] = pb; }
    if (f1 < P1_BLOCKS) { flen[f1] = L1; fofs[f1] = O1; fo[f1] = pb + L0; }
    if (t == P2_T - 1) stot = sc[t];
    __syncthreads();
    int sz = stot;
    if (sz > P2_CAP) sz = P2_CAP;   // never expected
    // cooperative fragment copy: 8-lane groups, fragment fb = wv*8+grp8 (+64 each)
    int wv = t >> 6, lane = t & 63;
    int grp8 = lane >> 3, l8 = lane & 7;
    for (int b = wv * 8 + grp8; b < P1_BLOCKS; b += 64) {
        int L = flen[b], O = fofs[b], F = fo[b];
        const int2* sp = coarse + (size_t)b * P1_EDGES + O;
        for (int j = l8; j < L; j += 8) {
            int dst2 = F + j;
            if (dst2 < P2_CAP) {
                int2 r = sp[j];
                pk[dst2] = r.x;
                vl[dst2] = r.y;
            }
        }
    }
    __syncthreads();
    hist[t] = 0;
    hist[t + P2_T] = 0;
    __syncthreads();
    int myrank[P2_ITERS];
#pragma unroll
    for (int k = 0; k < P2_ITERS; ++k) {
        int j = k * P2_T + t;
        myrank[k] = (j < sz) ? atomicAdd(&hist[((unsigned)pk[j]) >> 22], 1) : 0;
    }
    __syncthreads();
    int h0 = hist[2 * t], h1 = hist[2 * t + 1];
    sc[t] = h0 + h1;
    __syncthreads();
    for (int off = 1; off < P2_T; off <<= 1) {
        int x = (t >= off) ? sc[t - off] : 0;
        __syncthreads();
        sc[t] += x;
        __syncthreads();
    }
    int pbase = sc[t] - (h0 + h1);   // exclusive prefix of bin pair
    __syncthreads();
    hist[2 * t] = pbase;
    hist[2 * t + 1] = pbase + h0;
    // rp write (2 rows per thread)
    int which = (d >= NDIG_HALF);
    int lbase = basev[d] - (which ? E_NNZ : 0);
    int rowbase = (which ? d - NDIG_HALF : d) << 10;
    int* rp = which ? rpU : rpL;
    int r0 = rowbase + 2 * t, r1 = r0 + 1;
    if (r0 < N_SIMP) rp[r0] = lbase + pbase;
    if (r1 < N_SIMP) rp[r1] = lbase + pbase + h0;
    __syncthreads();
    int2* eout = which ? edgeU : edgeL;
#pragma unroll
    for (int k = 0; k < P2_ITERS; ++k) {
        int j = k * P2_T + t;
        if (j < sz) {
            unsigned p = (unsigned)pk[j];
            int pos = lbase + hist[p >> 22] + myrank[k];
            eout[pos] = make_int2((int)(p & 0x3FFFFF), vl[j]);
        }
    }
}

// ---------------- small prep kernels ----------------

__global__ void combine_bias_kernel(const float* __restrict__ bh,
                                    const float* __restrict__ bl,
                                    const float* __restrict__ bu,
                                    float* __restrict__ out) {
    int h = threadIdx.x;
    float acc = bh[h];
    for (int k = 0; k < KAPPA; ++k) acc += bl[k * HDIM + h] + bu[k * HDIM + h];
    out[h] = acc;
}

__global__ void f32_to_bf16_kernel(const float* __restrict__ in, bf16* __restrict__ out) {
    int idx = blockIdx.x * 256 + threadIdx.x;   // per float4
    float4 v = ((const float4*)in)[idx];
    ushort4 w;
    w.x = f2bf(v.x); w.y = f2bf(v.y); w.z = f2bf(v.z); w.w = f2bf(v.w);
    ((ushort4*)out)[idx] = w;
}

// all 6 weight transposes -> MFMA FRAGMENT layout, one dispatch.
// wfrag[(ch*4+nblk)*512 + lane*8 + j] = W[k = ch*32 + (lane>>4)*8 + j][nblk*16 + (lane&15)]
__global__ void wtrans_all_kernel(const float* __restrict__ s0, const float* __restrict__ s1,
                                  const float* __restrict__ s2, const float* __restrict__ s3,
                                  const float* __restrict__ s4, const float* __restrict__ s5,
                                  ushort* __restrict__ wt) {
    int idx = blockIdx.x * 256 + threadIdx.x;   // 0..43007
    const float* src; int off;
    if (idx < 2048)       { src = s0; off = 0; }
    else if (idx < 6144)  { src = s1; off = 2048; }
    else if (idx < 12288) { src = s2; off = 6144; }
    else if (idx < 18432) { src = s3; off = 12288; }
    else if (idx < 30720) { src = s4; off = 18432; }
    else                  { src = s5; off = 30720; }
    int rel = idx - off;
    int frag = rel >> 9;          // ch*4 + nblk
    int r = rel & 511;
    int lane = r >> 3, j = r & 7;
    int q = lane >> 4, n = lane & 15;
    int ch = frag >> 2, nblk = frag & 3;
    int k = ch * 32 + q * 8 + j;
    int nout = nblk * 16 + n;
    wt[idx] = f2bf(src[k * 64 + nout]);
}

// ---------------- SpMM (CSR gather) --------
// rp holds EXCLUSIVE row starts: s = rp[row], e = rp[row+1] (guarded at N-1)

// 32-wide: 4 lanes/row (8 ch each), 16 rows/wave, 64 rows/block
__global__ void spmm32_kernel(const int* __restrict__ rp, const int2* __restrict__ edge,
                              const bf16* __restrict__ srcb, int src_stride,
                              bf16* __restrict__ dstb) {
    const ushort* src = (const ushort*)srcb;
    ushort* dst = (ushort*)dstb;
    int tid = threadIdx.x;
    int lane = tid & 63;
    int wv = tid >> 6;
    int grp = lane >> 2;      // 0..15: row within wave
    int li = lane & 3;        // channels li*8 .. li*8+7
    int row = blockIdx.x * 64 + wv * 16 + grp;
    int s = rp[row];
    int e = (row == N_SIMP - 1) ? E_NNZ : rp[row + 1];
    int deg = e - s;
    float a[8] = {0.f, 0.f, 0.f, 0.f, 0.f, 0.f, 0.f, 0.f};
    if (deg > 0) {
        int2 ed[8];
#pragma unroll
        for (int t = 0; t < 8; ++t) {
            int j = s + t;
            ed[t] = edge[(j < e) ? j : (e - 1)];
        }
        u8v xs[8];
#pragma unroll
        for (int t = 0; t < 8; ++t)
            xs[t] = *(const u8v*)(src + (size_t)ed[t].x * src_stride + li * 8);
#pragma unroll
        for (int t = 0; t < 8; ++t) {
            float v = (t < deg) ? __int_as_float(ed[t].y) : 0.f;
#pragma unroll
            for (int c = 0; c < 8; ++c) a[c] += v * bf2f(xs[t][c]);
        }
        for (int j = s + 8; j < e; j += 4) {
            int2 e2[4];
#pragma unroll
            for (int t = 0; t < 4; ++t) {
                int jj = j + t;
                e2[t] = edge[(jj < e) ? jj : (e - 1)];
            }
            u8v x2[4];
#pragma unroll
            for (int t = 0; t < 4; ++t)
                x2[t] = *(const u8v*)(src + (size_t)e2[t].x * src_stride + li * 8);
#pragma unroll
            for (int t = 0; t < 4; ++t) {
                float v = (j + t < e) ? __int_as_float(e2[t].y) : 0.f;
#pragma unroll
                for (int c = 0; c < 8; ++c) a[c] += v * bf2f(x2[t][c]);
            }
        }
    }
    u8v w;
#pragma unroll
    for (int c = 0; c < 8; ++c) w[c] = f2bf(a[c]);
    *(u8v*)(dst + (size_t)row * 32 + li * 8) = w;
}

// 64-wide: 8 lanes/row (8 ch each), 8 rows/wave, 32 rows/block; stride 64
__global__ void spmm64_kernel(const int* __restrict__ rp, const int2* __restrict__ edge,
                              const bf16* __restrict__ srcb, bf16* __restrict__ dstb) {
    const ushort* src = (const ushort*)srcb;
    ushort* dst = (ushort*)dstb;
    int tid = threadIdx.x;
    int lane = tid & 63;
    int wv = tid >> 6;
    int grp = lane >> 3;      // 0..7: row within wave
    int li = lane & 7;        // channels li*8 .. li*8+7
    int row = blockIdx.x * 32 + wv * 8 + grp;
    int s = rp[row];
    int e = (row == N_SIMP - 1) ? E_NNZ : rp[row + 1];
    int deg = e - s;
    float a[8] = {0.f, 0.f, 0.f, 0.f, 0.f, 0.f, 0.f, 0.f};
    if (deg > 0) {
        int2 ed[8];
#pragma unroll
        for (int t = 0; t < 8; ++t) {
            int j = s + t;
            ed[t] = edge[(j < e) ? j : (e - 1)];
        }
        u8v xs[8];
#pragma unroll
        for (int t = 0; t < 8; ++t)
            xs[t] = *(const u8v*)(src + (size_t)ed[t].x * 64 + li * 8);
#pragma unroll
        for (int t = 0; t < 8; ++t) {
            float v = (t < deg) ? __int_as_float(ed[t].y) : 0.f;
#pragma unroll
            for (int c = 0; c < 8; ++c) a[c] += v * bf2f(xs[t][c]);
        }
        for (int j = s + 8; j < e; j += 4) {
            int2 e2[4];
#pragma unroll
            for (int t = 0; t < 4; ++t) {
                int jj = j + t;
                e2[t] = edge[(jj < e) ? jj : (e - 1)];
            }
            u8v x2[4];
#pragma unroll
            for (int t = 0; t < 4; ++t)
                x2[t] = *(const u8v*)(src + (size_t)e2[t].x * 64 + li * 8);
#pragma unroll
            for (int t = 0; t < 4; ++t) {
                float v = (j + t < e) ? __int_as_float(e2[t].y) : 0.f;
#pragma unroll
                for (int c = 0; c < 8; ++c) a[c] += v * bf2f(x2[t][c]);
            }
        }
    }
    u8v w;
#pragma unroll
    for (int c = 0; c < 8; ++c) w[c] = f2bf(a[c]);
    *(u8v*)(dst + (size_t)row * 64 + li * 8) = w;
}

// ---------------- MFMA GEMM: z[N,64] (fp16) (=bias+ / +=) A[N, NCH*32] @ W -------
// up to 6 A-channel sources; W in FRAGMENT layout (2048 ushorts per channel),
// split into two groups (Wt1 for ch<NCH1, Wt2 rest).
// STATS: fused BN-statistics accumulation of the FINAL z values (per-channel
// sum / sumsq via LDS float partials + one double atomicAdd per channel/block).

template <int NCH, int NCH1, bool INIT, bool STATS>
__global__ __launch_bounds__(256) void mfma_gemm_kernel(
        const ushort* __restrict__ s0, int st0,
        const ushort* __restrict__ s1, int st1,
        const ushort* __restrict__ s2, int st2,
        const ushort* __restrict__ s3, int st3,
        const ushort* __restrict__ s4, int st4,
        const ushort* __restrict__ s5, int st5,
        const ushort* __restrict__ Wt1,
        const ushort* __restrict__ Wt2,
        const float* __restrict__ bias,
        double* __restrict__ stats,
        f16* __restrict__ z) {
    __shared__ float s_sum[64], s_sq[64];
    int tid = threadIdx.x;
    int wv = tid >> 6, lane = tid & 63;
    int quad = lane >> 4, n = lane & 15;
    int rowbase = blockIdx.x * 64 + wv * 16;
    int arow = rowbase + n;  // A-operand row m = lane&15

    if (STATS) {
        if (tid < 64) { s_sum[tid] = 0.f; s_sq[tid] = 0.f; }
        __syncthreads();
    }

    f4v acc0 = {0.f, 0.f, 0.f, 0.f};
    f4v acc1 = {0.f, 0.f, 0.f, 0.f};
    f4v acc2 = {0.f, 0.f, 0.f, 0.f};
    f4v acc3 = {0.f, 0.f, 0.f, 0.f};

#pragma unroll
    for (int ch = 0; ch < NCH; ++ch) {
        const ushort* sp = (ch == 0) ? s0 : (ch == 1) ? s1 : (ch == 2) ? s2
                         : (ch == 3) ? s3 : (ch == 4) ? s4 : s5;
        int st = (ch == 0) ? st0 : (ch == 1) ? st1 : (ch == 2) ? st2
               : (ch == 3) ? st3 : (ch == 4) ? st4 : st5;
        const ushort* wb = (ch < NCH1) ? (Wt1 + (size_t)ch * 2048)
                                       : (Wt2 + (size_t)(ch - NCH1) * 2048);
        s8v a = *(const s8v*)(sp + (size_t)arow * st + quad * 8);
        const ushort* wq = wb + lane * 8;
        s8v b0 = *(const s8v*)(wq + 0 * 512);
        s8v b1 = *(const s8v*)(wq + 1 * 512);
        s8v b2 = *(const s8v*)(wq + 2 * 512);
        s8v b3 = *(const s8v*)(wq + 3 * 512);
        acc0 = __builtin_amdgcn_mfma_f32_16x16x32_bf16(a, b0, acc0, 0, 0, 0);
        acc1 = __builtin_amdgcn_mfma_f32_16x16x32_bf16(a, b1, acc1, 0, 0, 0);
        acc2 = __builtin_amdgcn_mfma_f32_16x16x32_bf16(a, b2, acc2, 0, 0, 0);
        acc3 = __builtin_amdgcn_mfma_f32_16x16x32_bf16(a, b3, acc3, 0, 0, 0);
    }
    // C/D layout: col = lane&15, row = quad*4 + reg
    float fs[4] = {0.f, 0.f, 0.f, 0.f};
    float fq[4] = {0.f, 0.f, 0.f, 0.f};
#pragma unroll
    for (int r = 0; r < 4; ++r) {
        int orow = rowbase + quad * 4 + r;
        f16* zp = z + (size_t)orow * 64 + n;
        f16 w0, w1, w2, w3;
        if (INIT) {
            w0 = (f16)(bias[n]      + acc0[r]);
            w1 = (f16)(bias[16 + n] + acc1[r]);
            w2 = (f16)(bias[32 + n] + acc2[r]);
            w3 = (f16)(bias[48 + n] + acc3[r]);
        } else {
            w0 = (f16)((float)zp[0]  + acc0[r]);
            w1 = (f16)((float)zp[16] + acc1[r]);
            w2 = (f16)((float)zp[32] + acc2[r]);
            w3 = (f16)((float)zp[48] + acc3[r]);
        }
        zp[0] = w0; zp[16] = w1; zp[32] = w2; zp[48] = w3;
        if (STATS) {
            float v0 = (float)w0, v1 = (float)w1, v2 = (float)w2, v3 = (float)w3;
            fs[0] += v0; fq[0] += v0 * v0;
            fs[1] += v1; fq[1] += v1 * v1;
            fs[2] += v2; fq[2] += v2 * v2;
            fs[3] += v3; fq[3] += v3 * v3;
        }
    }
    if (STATS) {
#pragma unroll
        for (int k = 0; k < 4; ++k) {
            atomicAdd(&s_sum[k * 16 + n], fs[k]);
            atomicAdd(&s_sq[k * 16 + n], fq[k]);
        }
        __syncthreads();
        if (tid < 64) {
            atomicAdd(&stats[tid], (double)s_sum[tid]);
            atomicAdd(&stats[64 + tid], (double)s_sq[tid]);
        }
    }
}

// ---------------- BN / pool / MLP (vectorized) ----------------

// layer-0: h0bf = bf16(elu(bn(z)))
__global__ void bn_elu_bf16_kernel(const f16* __restrict__ z, const double* __restrict__ stats,
                                   const float* __restrict__ gamma, const float* __restrict__ beta,
                                   bf16* __restrict__ out) {
    __shared__ float scale_s[64], shift_s[64];
    int tid = threadIdx.x;
    if (tid < 64) {
        double mean = stats[tid] / (double)N_SIMP;
        double var = stats[64 + tid] / (double)N_SIMP - mean * mean;
        double sc = (double)gamma[tid] / sqrt(var + BN_EPS);
        scale_s[tid] = (float)sc;
        shift_s[tid] = (float)((double)beta[tid] - mean * sc);
    }
    __syncthreads();
    const h8v* z8 = (const h8v*)z;
    u8v* o8 = (u8v*)out;
    const int total8 = N_SIMP * HDIM / 8;
    int hb = (tid & 7) * 8;
    for (int i = blockIdx.x * 256 + tid; i < total8; i += (int)gridDim.x * 256) {
        h8v v = z8[i];
        u8v w;
#pragma unroll
        for (int c = 0; c < 8; ++c)
            w[c] = f2bf(elu_f((float)v[c] * scale_s[hb + c] + shift_s[hb + c]));
        o8[i] = w;
    }
}

// fused bn1 + elu + global max/mean pool: reads raw z, applies elu(bn(z)) inline.
// 8 lanes/row (h8v = 16B each), 32 rows in flight per 256-thread block.
__global__ void pool_bn_kernel(const f16* __restrict__ zbuf, const int* __restrict__ bidx,
                               const double* __restrict__ stats,
                               const float* __restrict__ gamma, const float* __restrict__ beta,
                               float* __restrict__ gbuf) {
    __shared__ float scale_s[64], shift_s[64];
    __shared__ float pmax[256 * 8], psum[256 * 8];
    int tid = threadIdx.x;
    if (tid < 64) {
        double mean = stats[tid] / (double)N_SIMP;
        double var = stats[64 + tid] / (double)N_SIMP - mean * mean;
        double sc = (double)gamma[tid] / sqrt(var + BN_EPS);
        scale_s[tid] = (float)sc;
        shift_s[tid] = (float)((double)beta[tid] - mean * sc);
    }
    __syncthreads();
    int g = blockIdx.x;
    int lo = 0, hi = N_SIMP;
    while (lo < hi) { int mid = (lo + hi) >> 1; if (bidx[mid] < g) lo = mid + 1; else hi = mid; }
    int start = lo;
    hi = N_SIMP;
    while (lo < hi) { int mid = (lo + hi) >> 1; if (bidx[mid] < g + 1) lo = mid + 1; else hi = mid; }
    int end = lo;
    int li = tid & 7;        // channel block: li*8 .. li*8+7
    int rr = tid >> 3;       // row offset 0..31
    const h8v* z8 = (const h8v*)zbuf;
    float mx[8], sm[8];
#pragma unroll
    for (int c = 0; c < 8; ++c) { mx[c] = -INFINITY; sm[c] = 0.f; }
    float sc8[8], sh8[8];
#pragma unroll
    for (int c = 0; c < 8; ++c) { sc8[c] = scale_s[li * 8 + c]; sh8[c] = shift_s[li * 8 + c]; }
    for (int i = start + rr; i < end; i += 32) {
        h8v v = z8[(size_t)i * 8 + li];
#pragma unroll
        for (int c = 0; c < 8; ++c) {
            float y = elu_f((float)v[c] * sc8[c] + sh8[c]);
            mx[c] = fmaxf(mx[c], y);
            sm[c] += y;
        }
    }
#pragma unroll
    for (int c = 0; c < 8; ++c) { pmax[tid * 8 + c] = mx[c]; psum[tid * 8 + c] = sm[c]; }
    __syncthreads();
    if (tid < 64) {
        int sel = tid >> 3, slot = tid & 7;   // li = sel, c = slot
        float m = -INFINITY, s = 0.f;
#pragma unroll 8
        for (int k = 0; k < 32; ++k) {
            int t = k * 8 + sel;
            m = fmaxf(m, pmax[t * 8 + slot]);
            s += psum[t * 8 + slot];
        }
        int cnt = end - start;
        float mean = s / fmaxf((float)cnt, 1.f);
        gbuf[g * 128 + tid] = elu_f(m);
        gbuf[g * 128 + 64 + tid] = elu_f(mean);
    }
}

__global__ void mlp_kernel(const float* __restrict__ gbuf, const float* __restrict__ W1,
                           const float* __restrict__ b1, const float* __restrict__ W2,
                           const float* __restrict__ b2, float* __restrict__ out) {
    __shared__ float gs[128];
    __shared__ float hs[64];
    int g = blockIdx.x, tid = threadIdx.x;
    gs[tid] = gbuf[g * 128 + tid];
    gs[64 + tid] = gbuf[g * 128 + 64 + tid];
    __syncthreads();
    float acc = b1[tid];
#pragma unroll
    for (int k = 0; k < 128; ++k) acc += gs[k] * W1[k * 64 + tid];
    hs[tid] = fmaxf(acc, 0.f);
    __syncthreads();
    if (tid < 8) {
        float o = b2[tid];
#pragma unroll
        for (int k = 0; k < 64; ++k) o += hs[k] * W2[k * 8 + tid];
        out[g * 8 + tid] = o;
    }
}

// ---------------- host side ----------------

extern "C" void kernel_launch(void* const* d_in, const int* in_sizes, int n_in,
                              void* d_out, int out_size, void* d_ws, size_t ws_size,
                              hipStream_t stream) {
    const float* x     = (const float*)d_in[0];
    const int*   li    = (const int*)d_in[1];
    const float* lv    = (const float*)d_in[2];
    const int*   ui    = (const int*)d_in[3];
    const float* uv    = (const float*)d_in[4];
    const int*   bidx  = (const int*)d_in[5];
    const float* l0_Wl = (const float*)d_in[6];
    const float* l0_bl = (const float*)d_in[7];
    const float* l0_Wu = (const float*)d_in[8];
    const float* l0_bu = (const float*)d_in[9];
    const float* l0_Wh = (const float*)d_in[10];
    const float* l0_bh = (const float*)d_in[11];
    const float* l1_Wl = (const float*)d_in[12];
    const float* l1_bl = (const float*)d_in[13];
    const float* l1_Wu = (const float*)d_in[14];
    const float* l1_bu = (const float*)d_in[15];
    const float* l1_Wh = (const float*)d_in[16];
    const float* l1_bh = (const float*)d_in[17];
    const float* bn0_g = (const float*)d_in[18];
    const float* bn0_b = (const float*)d_in[19];
    const float* bn1_g = (const float*)d_in[20];
    const float* bn1_b = (const float*)d_in[21];
    const float* mW1   = (const float*)d_in[22];
    const float* mb1   = (const float*)d_in[23];
    const float* mW2   = (const float*)d_in[24];
    const float* mb2   = (const float*)d_in[25];
    float* out = (float*)d_out;

    // ---- workspace layout (total ~246.8 MB <= 256 MiB) ----
    char* base = (char*)d_ws;
    f16*   z     = (f16*)base;                                    //  51,200,000
    bf16*  h0bf  = (bf16*)(base + 51200000ull);                   //  51,200,000
    bf16*  g1    = (bf16*)(base + 102400000ull);                  //  51,200,000
    bf16*  g2    = (bf16*)(base + 153600000ull);                  //  51,200,000
    int2*  edgeL = (int2*)(base + 204800000ull);                  //  19,200,000
    int2*  edgeU = (int2*)(base + 224000000ull);                  //  19,200,000
    int*   rpL   = (int*)(base + 243200000ull);                   //   1,600,032
    int*   rpU   = (int*)(base + 244800032ull);                   //   1,600,032
    double* stats = (double*)(base + 246404160ull);               //   1 KB
    float* cbias  = (float*)(base + 246405184ull);                //   256 B
    float* gbuf   = (float*)(base + 246405440ull);                //   262,144
    ushort* wt    = (ushort*)(base + 246667584ull);               //   86,016

    // CSR-build scratch aliases (regions dead during build):
    //  z region   : coarse 38.4 MB + basev 3.1 KB
    //  h0bf region: ccnt 1.83 MB + bofs 1.83 MB
    int2* coarse = (int2*)base;                                   // 38,404,096
    int*  basev  = (int*)(base + 38500000ull);                    // (NDIG+1)*4
    int*  ccnt   = (int*)(base + 51200000ull);                    // 1,833,008
    int*  bofsv  = (int*)(base + 53100000ull);                    // 1,833,008

    // layer-0 scratch: 6 slots of N*32 bf16 in g1/g2/h0bf regions
    bf16* xbf  = g1;                                 // g1 slot 0 (later cCU)
    bf16* cAL  = g1 + (size_t)N_SIMP * 32;           // g1 slot 1
    bf16* cBL  = g2;                                 // g2 slot 0
    bf16* cCL  = g2 + (size_t)N_SIMP * 32;           // g2 slot 1
    bf16* cAU  = h0bf;                               // h0 slot 0
    bf16* cBU  = h0bf + (size_t)N_SIMP * 32;         // h0 slot 1
    bf16* cCU  = g1;                                 // reuses xbf slot (xbf dead)

    // weight-fragment sub-buffers (ushort elements; 2048 ushorts per channel)
    ushort* wt_l0h = wt;            // 1 ch  (K=32)
    ushort* wt_l1h = wt + 2048;     // 2 ch  (K=64)
    ushort* wt_l0l = wt + 6144;     // 3 ch  (K=96)
    ushort* wt_l0u = wt + 12288;    // 3 ch  (K=96)
    ushort* wt_l1l = wt + 18432;    // 6 ch  (K=192)
    ushort* wt_l1u = wt + 30720;    // 6 ch  (K=192)

    const int SP32_BLOCKS = N_SIMP / 64;   // 6,250
    const int SP64_BLOCKS = N_SIMP / 32;   // 12,500
    const int MF_BLOCKS   = N_SIMP / 64;   // 6,250

    // ---- prep: weight transposes (one dispatch) + x->bf16 ----
    wtrans_all_kernel<<<168, 256, 0, stream>>>(l0_Wh, l1_Wh, l0_Wl, l0_Wu, l1_Wl, l1_Wu, wt);
    f32_to_bf16_kernel<<<N_SIMP * 32 / 4 / 256, 256, 0, stream>>>(x, xbf);

    // ---- CSR builds: in-LDS block sort + fragment-gather bucket sort ----
    p1_sort_kernel<<<P1_BLOCKS, P1_T, 0, stream>>>(li, lv, ui, uv, ccnt, bofsv, coarse);
    digit_total_kernel<<<(NDIG + 255) / 256, 256, 0, stream>>>(ccnt, basev);
    scan_base_kernel<<<1, 1024, 0, stream>>>(basev);
    p2_build_kernel<<<NDIG, P2_T, 0, stream>>>(coarse, ccnt, bofsv, basev,
                                               rpL, rpU, edgeL, edgeU);

    const ushort* xbfu = (const ushort*)xbf;
    const ushort* h0u  = (const ushort*)h0bf;
    const ushort* g1u  = (const ushort*)g1;
    const ushort* g2u  = (const ushort*)g2;

    // ---------------- layer 0 (F_IN=32 -> H=64) ----------------
    combine_bias_kernel<<<1, 64, 0, stream>>>(l0_bh, l0_bl, l0_bu, cbias);
    (void)hipMemsetAsync(stats, 0, 128 * sizeof(double), stream);
    mfma_gemm_kernel<1, 1, true, false><<<MF_BLOCKS, 256, 0, stream>>>(
        xbfu, 32, nullptr, 0, nullptr, 0, nullptr, 0, nullptr, 0, nullptr, 0,
        wt_l0h, wt_l0h, cbias, nullptr, z);

    // lower chain
    spmm32_kernel<<<SP32_BLOCKS, 256, 0, stream>>>(rpL, edgeL, xbf, 32, cAL);
    spmm32_kernel<<<SP32_BLOCKS, 256, 0, stream>>>(rpL, edgeL, cAL, 32, cBL);
    spmm32_kernel<<<SP32_BLOCKS, 256, 0, stream>>>(rpL, edgeL, cBL, 32, cCL);
    // upper chain (cAU spmm reads xbf before cCU overwrites that slot)
    spmm32_kernel<<<SP32_BLOCKS, 256, 0, stream>>>(rpU, edgeU, xbf, 32, cAU);
    spmm32_kernel<<<SP32_BLOCKS, 256, 0, stream>>>(rpU, edgeU, cAU, 32, cBU);
    spmm32_kernel<<<SP32_BLOCKS, 256, 0, stream>>>(rpU, edgeU, cBU, 32, cCU);
    // single accumulate-GEMM over all 6 chain outputs, with fused BN0 stats
    mfma_gemm_kernel<6, 3, false, true><<<MF_BLOCKS, 256, 0, stream>>>(
        (const ushort*)cAL, 32, (const ushort*)cBL, 32, (const ushort*)cCL, 32,
        (const ushort*)cAU, 32, (const ushort*)cBU, 32, (const ushort*)cCU, 32,
        wt_l0l, wt_l0u, nullptr, stats, z);

    bn_elu_bf16_kernel<<<1024, 256, 0, stream>>>(z, stats, bn0_g, bn0_b, h0bf);

    // ---------------- layer 1 (H=64 -> H=64), 64-wide chains ----------------
    combine_bias_kernel<<<1, 64, 0, stream>>>(l1_bh, l1_bl, l1_bu, cbias);
    (void)hipMemsetAsync(stats, 0, 128 * sizeof(double), stream);

    // u1 = L h0 -> g1 ; u2 = L u1 -> g2
    spmm64_kernel<<<SP64_BLOCKS, 256, 0, stream>>>(rpL, edgeL, h0bf, g1);
    spmm64_kernel<<<SP64_BLOCKS, 256, 0, stream>>>(rpL, edgeL, g1, g2);
    // gemm A (INIT): h0 (wt_l1h ch 0-1), u1+u2 (wt_l1l ch 0-3), + bias
    mfma_gemm_kernel<6, 2, true, false><<<MF_BLOCKS, 256, 0, stream>>>(
        h0u, 64, h0u + 32, 64, g1u, 64, g1u + 32, 64, g2u, 64, g2u + 32, 64,
        wt_l1h, wt_l1l, cbias, nullptr, z);
    // u3 = L u2 -> g1 ; v1 = U h0 -> g2
    spmm64_kernel<<<SP64_BLOCKS, 256, 0, stream>>>(rpL, edgeL, g2, g1);
    spmm64_kernel<<<SP64_BLOCKS, 256, 0, stream>>>(rpU, edgeU, h0bf, g2);
    // gemm B: u3 (wt_l1l ch 4-5), v1 (wt_l1u ch 0-1)
    mfma_gemm_kernel<4, 2, false, false><<<MF_BLOCKS, 256, 0, stream>>>(
        g1u, 64, g1u + 32, 64, g2u, 64, g2u + 32, 64, nullptr, 0, nullptr, 0,
        wt_l1l + 4 * 2048, wt_l1u, nullptr, nullptr, z);
    // v2 = U v1 -> g1 ; v3 = U v2 -> g2
    spmm64_kernel<<<SP64_BLOCKS, 256, 0, stream>>>(rpU, edgeU, g2, g1);
    spmm64_kernel<<<SP64_BLOCKS, 256, 0, stream>>>(rpU, edgeU, g1, g2);
    // gemm C: v2+v3 (wt_l1u ch 2-5), with fused BN1 stats (z final here)
    mfma_gemm_kernel<4, 4, false, true><<<MF_BLOCKS, 256, 0, stream>>>(
        g1u, 64, g1u + 32, 64, g2u, 64, g2u + 32, 64, nullptr, 0, nullptr, 0,
        wt_l1u + 2 * 2048, wt_l1u + 2 * 2048, nullptr, stats, z);

    // ---------------- fused bn1+elu+pool, then MLP ----------------
    pool_bn_kernel<<<G_NUM, 256, 0, stream>>>(z, bidx, stats, bn1_g, bn1_b, gbuf);
    mlp_kernel<<<G_NUM, 64, 0, stream>>>(gbuf, mW1, mb1, mW2, mb2, out);
}

// Round 10
// 1233.828 us; speedup vs baseline: 1.1086x; 1.1086x over previous
//
#include <hip/hip_runtime.h>
#include <hip/hip_bf16.h>
#include <math.h>

#define N_SIMP 400000
#define E_NNZ  2400000
#define FIN    32
#define HDIM   64
#define KAPPA  3
#define G_NUM  512
#define NOUT   8
#define BN_EPS 1e-5

// ---- CSR build (two-level LDS counting sort; pass-1 sorts fully in LDS) ----
#define NDIG_HALF 391             // ceil(400000/1024) coarse buckets per matrix
#define NDIG      782             // L + U
#define P1_EDGES  8192            // edges per pass-1 block (8/thread @ 1024 thr)
#define P1_BLOCKS 586             // ceil(4.8M / 8192)
#define P1_T      1024
#define P1_EPT    8
#define P2_CAP    7168            // bucket capacity (avg 6144, +13 sigma headroom)
#define P2_T      512
#define P2_ITERS  14              // P2_CAP / P2_T

#define MF_BLOCKS_C 6250          // N_SIMP / 64 (STATS partial rows)

typedef __hip_bfloat16 bf16;
typedef _Float16 f16;
typedef short s8v __attribute__((ext_vector_type(8)));    // 8 bf16 in 4 VGPRs
typedef ushort u8v __attribute__((ext_vector_type(8)));   // 8 bf16 raw
typedef _Float16 h8v __attribute__((ext_vector_type(8))); // 8 f16
typedef float f4v __attribute__((ext_vector_type(4)));

__device__ __forceinline__ float elu_f(float x) {
    return x > 0.f ? x : expm1f(x);
}
__device__ __forceinline__ float bf2f(ushort u) {
    return __uint_as_float(((unsigned int)u) << 16);
}
__device__ __forceinline__ ushort f2bf(float f) {
    bf16 h = (bf16)f;
    return *(ushort*)&h;
}

// ---------------- CSR build: pass 1 (full in-LDS counting sort per block) -------

__global__ __launch_bounds__(P1_T) void p1_sort_kernel(
        const int* __restrict__ eiL, const float* __restrict__ lv,
        const int* __restrict__ eiU, const float* __restrict__ uv,
        int* __restrict__ ccnt, int* __restrict__ bofsv,
        int2* __restrict__ coarse) {
    __shared__ int2 rec[P1_EDGES];   // 64 KB
    __shared__ int h[NDIG];          // counts -> running offsets
    __shared__ int hscan[P1_T];      // scan scratch
    int t = threadIdx.x;
    for (int j = t; j < NDIG; j += P1_T) h[j] = 0;
    __syncthreads();
    int base_i = blockIdx.x * P1_EDGES;
    int key[P1_EPT], val[P1_EPT], dg[P1_EPT];
#pragma unroll
    for (int k = 0; k < P1_EPT; ++k) {
        int i = base_i + k * P1_T + t;
        int dd = -1;
        if (i < 2 * E_NNZ) {
            int row, col;
            float v;
            if (i < E_NNZ) {
                row = eiL[i]; col = eiL[E_NNZ + i]; v = lv[i];
                dd = row >> 10;
            } else {
                int e = i - E_NNZ;
                row = eiU[e]; col = eiU[E_NNZ + e]; v = uv[e];
                dd = NDIG_HALF + (row >> 10);
            }
            key[k] = ((row & 1023) << 22) | col;
            val[k] = __float_as_int(v);
            atomicAdd(&h[dd], 1);
        }
        dg[k] = dd;
    }
    __syncthreads();
    // scan the 782 counts (1024-thread Hillis-Steele); emit ccnt/bofs; h := excl.
    int cv = (t < NDIG) ? h[t] : 0;
    hscan[t] = cv;
    __syncthreads();
    for (int off = 1; off < P1_T; off <<= 1) {
        int x = (t >= off) ? hscan[t - off] : 0;
        __syncthreads();
        hscan[t] += x;
        __syncthreads();
    }
    if (t < NDIG) {
        int ex = hscan[t] - cv;
        ccnt[blockIdx.x * NDIG + t] = cv;
        bofsv[blockIdx.x * NDIG + t] = ex;
        h[t] = ex;
    }
    __syncthreads();
    // placement into digit-sorted LDS buffer
#pragma unroll
    for (int k = 0; k < P1_EPT; ++k) {
        if (dg[k] >= 0) {
            int pos = atomicAdd(&h[dg[k]], 1);
            rec[pos] = make_int2(key[k], val[k]);
        }
    }
    __syncthreads();
    // contiguous stream-out: full-line writes only
    int2* dst = coarse + (size_t)blockIdx.x * P1_EDGES;
    int nrec = 2 * E_NNZ - base_i;
    if (nrec > P1_EDGES) nrec = P1_EDGES;
    for (int j = t; j < nrec; j += P1_T) dst[j] = rec[j];
}

// per-digit totals over blocks
__global__ void digit_total_kernel(const int* __restrict__ cnt, int* __restrict__ tot) {
    int d = blockIdx.x * 256 + threadIdx.x;
    if (d >= NDIG) return;
    int run = 0;
    for (int b = 0; b < P1_BLOCKS; ++b) run += cnt[b * NDIG + d];
    tot[d] = run;
}

// exclusive scan of tot[NDIG] in place (becomes digit global base)
__global__ __launch_bounds__(1024) void scan_base_kernel(int* __restrict__ tot) {
    __shared__ int s[1024];
    int t = threadIdx.x;
    int v = (t < NDIG) ? tot[t] : 0;
    s[t] = v;
    __syncthreads();
    for (int off = 1; off < 1024; off <<= 1) {
        int x = (t >= off) ? s[t - off] : 0;
        __syncthreads();
        s[t] += x;
        __syncthreads();
    }
    if (t < NDIG) tot[t] = s[t] - v;
    if (t == 1023) tot[NDIG] = s[1023];   // = 2*E_NNZ
}

// ---------------- CSR build: pass 2 (fragment gather + LDS counting sort) -------

__global__ __launch_bounds__(P2_T) void p2_build_kernel(
        const int2* __restrict__ coarse, const int* __restrict__ ccnt,
        const int* __restrict__ bofsv, const int* __restrict__ basev,
        int* __restrict__ rpL, int* __restrict__ rpU,
        int2* __restrict__ edgeL, int2* __restrict__ edgeU) {
    __shared__ int pk[P2_CAP];
    __shared__ int vl[P2_CAP];
    __shared__ int hist[1024];
    __shared__ int sc[P2_T];
    __shared__ int flen[P1_BLOCKS];
    __shared__ int fofs[P1_BLOCKS];
    __shared__ int fo[P1_BLOCKS];
    __shared__ int stot;
    int d = blockIdx.x;
    int t = threadIdx.x;
    // fragment table: 586 fragments; thread t handles fragments 2t, 2t+1 (pair scan)
    int f0 = 2 * t, f1 = 2 * t + 1;
    int L0 = 0, L1 = 0, O0 = 0, O1 = 0;
    if (f0 < P1_BLOCKS) { L0 = ccnt[f0 * NDIG + d]; O0 = bofsv[f0 * NDIG + d]; }
    if (f1 < P1_BLOCKS) { L1 = ccnt[f1 * NDIG + d]; O1 = bofsv[f1 * NDIG + d]; }
    sc[t] = L0 + L1;
    __syncthreads();
    for (int off = 1; off < P2_T; off <<= 1) {
        int x = (t >= off) ? sc[t - off] : 0;
        __syncthreads();
        sc[t] += x;
        __syncthreads();
    }
    int pb = sc[t] - (L0 + L1);
    if (f0 < P1_BLOCKS) { flen[f0] = L0; fofs[f0] = O0; fo[f0] = pb; }
    if (f1 < P1_BLOCKS) { flen[f1] = L1; fofs[f1] = O1; fo[f1] = pb + L0; }
    if (t == P2_T - 1) stot = sc[t];
    __syncthreads();
    int sz = stot;
    if (sz > P2_CAP) sz = P2_CAP;   // never expected
    // cooperative fragment copy: 8-lane groups, fragment fb = wv*8+grp8 (+64 each)
    int wv = t >> 6, lane = t & 63;
    int grp8 = lane >> 3, l8 = lane & 7;
    for (int b = wv * 8 + grp8; b < P1_BLOCKS; b += 64) {
        int L = flen[b], O = fofs[b], F = fo[b];
        const int2* sp = coarse + (size_t)b * P1_EDGES + O;
        for (int j = l8; j < L; j += 8) {
            int dst2 = F + j;
            if (dst2 < P2_CAP) {
                int2 r = sp[j];
                pk[dst2] = r.x;
                vl[dst2] = r.y;
            }
        }
    }
    __syncthreads();
    hist[t] = 0;
    hist[t + P2_T] = 0;
    __syncthreads();
    int myrank[P2_ITERS];
#pragma unroll
    for (int k = 0; k < P2_ITERS; ++k) {
        int j = k * P2_T + t;
        myrank[k] = (j < sz) ? atomicAdd(&hist[((unsigned)pk[j]) >> 22], 1) : 0;
    }
    __syncthreads();
    int h0 = hist[2 * t], h1 = hist[2 * t + 1];
    sc[t] = h0 + h1;
    __syncthreads();
    for (int off = 1; off < P2_T; off <<= 1) {
        int x = (t >= off) ? sc[t - off] : 0;
        __syncthreads();
        sc[t] += x;
        __syncthreads();
    }
    int pbase = sc[t] - (h0 + h1);   // exclusive prefix of bin pair
    __syncthreads();
    hist[2 * t] = pbase;
    hist[2 * t + 1] = pbase + h0;
    // rp write (2 rows per thread)
    int which = (d >= NDIG_HALF);
    int lbase = basev[d] - (which ? E_NNZ : 0);
    int rowbase = (which ? d - NDIG_HALF : d) << 10;
    int* rp = which ? rpU : rpL;
    int r0 = rowbase + 2 * t, r1 = r0 + 1;
    if (r0 < N_SIMP) rp[r0] = lbase + pbase;
    if (r1 < N_SIMP) rp[r1] = lbase + pbase + h0;
    __syncthreads();
    int2* eout = which ? edgeU : edgeL;
#pragma unroll
    for (int k = 0; k < P2_ITERS; ++k) {
        int j = k * P2_T + t;
        if (j < sz) {
            unsigned p = (unsigned)pk[j];
            int pos = lbase + hist[p >> 22] + myrank[k];
            eout[pos] = make_int2((int)(p & 0x3FFFFF), vl[j]);
        }
    }
}

// ---------------- small prep kernels ----------------

__global__ void combine_bias_kernel(const float* __restrict__ bh,
                                    const float* __restrict__ bl,
                                    const float* __restrict__ bu,
                                    float* __restrict__ out) {
    int h = threadIdx.x;
    float acc = bh[h];
    for (int k = 0; k < KAPPA; ++k) acc += bl[k * HDIM + h] + bu[k * HDIM + h];
    out[h] = acc;
}

__global__ void f32_to_bf16_kernel(const float* __restrict__ in, bf16* __restrict__ out) {
    int idx = blockIdx.x * 256 + threadIdx.x;   // per float4
    float4 v = ((const float4*)in)[idx];
    ushort4 w;
    w.x = f2bf(v.x); w.y = f2bf(v.y); w.z = f2bf(v.z); w.w = f2bf(v.w);
    ((ushort4*)out)[idx] = w;
}

// all 6 weight transposes -> MFMA FRAGMENT layout, one dispatch.
// wfrag[(ch*4+nblk)*512 + lane*8 + j] = W[k = ch*32 + (lane>>4)*8 + j][nblk*16 + (lane&15)]
__global__ void wtrans_all_kernel(const float* __restrict__ s0, const float* __restrict__ s1,
                                  const float* __restrict__ s2, const float* __restrict__ s3,
                                  const float* __restrict__ s4, const float* __restrict__ s5,
                                  ushort* __restrict__ wt) {
    int idx = blockIdx.x * 256 + threadIdx.x;   // 0..43007
    const float* src; int off;
    if (idx < 2048)       { src = s0; off = 0; }
    else if (idx < 6144)  { src = s1; off = 2048; }
    else if (idx < 12288) { src = s2; off = 6144; }
    else if (idx < 18432) { src = s3; off = 12288; }
    else if (idx < 30720) { src = s4; off = 18432; }
    else                  { src = s5; off = 30720; }
    int rel = idx - off;
    int frag = rel >> 9;          // ch*4 + nblk
    int r = rel & 511;
    int lane = r >> 3, j = r & 7;
    int q = lane >> 4, n = lane & 15;
    int ch = frag >> 2, nblk = frag & 3;
    int k = ch * 32 + q * 8 + j;
    int nout = nblk * 16 + n;
    wt[idx] = f2bf(src[k * 64 + nout]);
}

// ---------------- SpMM (CSR gather) --------
// rp holds EXCLUSIVE row starts: s = rp[row], e = rp[row+1] (guarded at N-1)

// 32-wide: 4 lanes/row (8 ch each), 16 rows/wave, 64 rows/block
__global__ void spmm32_kernel(const int* __restrict__ rp, const int2* __restrict__ edge,
                              const bf16* __restrict__ srcb, int src_stride,
                              bf16* __restrict__ dstb) {
    const ushort* src = (const ushort*)srcb;
    ushort* dst = (ushort*)dstb;
    int tid = threadIdx.x;
    int lane = tid & 63;
    int wv = tid >> 6;
    int grp = lane >> 2;      // 0..15: row within wave
    int li = lane & 3;        // channels li*8 .. li*8+7
    int row = blockIdx.x * 64 + wv * 16 + grp;
    int s = rp[row];
    int e = (row == N_SIMP - 1) ? E_NNZ : rp[row + 1];
    int deg = e - s;
    float a[8] = {0.f, 0.f, 0.f, 0.f, 0.f, 0.f, 0.f, 0.f};
    if (deg > 0) {
        int2 ed[8];
#pragma unroll
        for (int t = 0; t < 8; ++t) {
            int j = s + t;
            ed[t] = edge[(j < e) ? j : (e - 1)];
        }
        u8v xs[8];
#pragma unroll
        for (int t = 0; t < 8; ++t)
            xs[t] = *(const u8v*)(src + (size_t)ed[t].x * src_stride + li * 8);
#pragma unroll
        for (int t = 0; t < 8; ++t) {
            float v = (t < deg) ? __int_as_float(ed[t].y) : 0.f;
#pragma unroll
            for (int c = 0; c < 8; ++c) a[c] += v * bf2f(xs[t][c]);
        }
        for (int j = s + 8; j < e; j += 4) {
            int2 e2[4];
#pragma unroll
            for (int t = 0; t < 4; ++t) {
                int jj = j + t;
                e2[t] = edge[(jj < e) ? jj : (e - 1)];
            }
            u8v x2[4];
#pragma unroll
            for (int t = 0; t < 4; ++t)
                x2[t] = *(const u8v*)(src + (size_t)e2[t].x * src_stride + li * 8);
#pragma unroll
            for (int t = 0; t < 4; ++t) {
                float v = (j + t < e) ? __int_as_float(e2[t].y) : 0.f;
#pragma unroll
                for (int c = 0; c < 8; ++c) a[c] += v * bf2f(x2[t][c]);
            }
        }
    }
    u8v w;
#pragma unroll
    for (int c = 0; c < 8; ++c) w[c] = f2bf(a[c]);
    *(u8v*)(dst + (size_t)row * 32 + li * 8) = w;
}

// 64-wide: 8 lanes/row (8 ch each), 8 rows/wave, 32 rows/block; stride 64
__global__ void spmm64_kernel(const int* __restrict__ rp, const int2* __restrict__ edge,
                              const bf16* __restrict__ srcb, bf16* __restrict__ dstb) {
    const ushort* src = (const ushort*)srcb;
    ushort* dst = (ushort*)dstb;
    int tid = threadIdx.x;
    int lane = tid & 63;
    int wv = tid >> 6;
    int grp = lane >> 3;      // 0..7: row within wave
    int li = lane & 7;        // channels li*8 .. li*8+7
    int row = blockIdx.x * 32 + wv * 8 + grp;
    int s = rp[row];
    int e = (row == N_SIMP - 1) ? E_NNZ : rp[row + 1];
    int deg = e - s;
    float a[8] = {0.f, 0.f, 0.f, 0.f, 0.f, 0.f, 0.f, 0.f};
    if (deg > 0) {
        int2 ed[8];
#pragma unroll
        for (int t = 0; t < 8; ++t) {
            int j = s + t;
            ed[t] = edge[(j < e) ? j : (e - 1)];
        }
        u8v xs[8];
#pragma unroll
        for (int t = 0; t < 8; ++t)
            xs[t] = *(const u8v*)(src + (size_t)ed[t].x * 64 + li * 8);
#pragma unroll
        for (int t = 0; t < 8; ++t) {
            float v = (t < deg) ? __int_as_float(ed[t].y) : 0.f;
#pragma unroll
            for (int c = 0; c < 8; ++c) a[c] += v * bf2f(xs[t][c]);
        }
        for (int j = s + 8; j < e; j += 4) {
            int2 e2[4];
#pragma unroll
            for (int t = 0; t < 4; ++t) {
                int jj = j + t;
                e2[t] = edge[(jj < e) ? jj : (e - 1)];
            }
            u8v x2[4];
#pragma unroll
            for (int t = 0; t < 4; ++t)
                x2[t] = *(const u8v*)(src + (size_t)e2[t].x * 64 + li * 8);
#pragma unroll
            for (int t = 0; t < 4; ++t) {
                float v = (j + t < e) ? __int_as_float(e2[t].y) : 0.f;
#pragma unroll
                for (int c = 0; c < 8; ++c) a[c] += v * bf2f(x2[t][c]);
            }
        }
    }
    u8v w;
#pragma unroll
    for (int c = 0; c < 8; ++c) w[c] = f2bf(a[c]);
    *(u8v*)(dst + (size_t)row * 64 + li * 8) = w;
}

// ---------------- MFMA GEMM: z[N,64] (fp16) (=bias+ / +=) A[N, NCH*32] @ W -------
// up to 6 A-channel sources; W in FRAGMENT layout (2048 ushorts per channel),
// split into two groups (Wt1 for ch<NCH1, Wt2 rest).
// STATS: fused BN-statistics of FINAL z values -> per-block float partials
// (contention-free coalesced store; reduced by stats_reduce_kernel).

template <int NCH, int NCH1, bool INIT, bool STATS>
__global__ __launch_bounds__(256) void mfma_gemm_kernel(
        const ushort* __restrict__ s0, int st0,
        const ushort* __restrict__ s1, int st1,
        const ushort* __restrict__ s2, int st2,
        const ushort* __restrict__ s3, int st3,
        const ushort* __restrict__ s4, int st4,
        const ushort* __restrict__ s5, int st5,
        const ushort* __restrict__ Wt1,
        const ushort* __restrict__ Wt2,
        const float* __restrict__ bias,
        float* __restrict__ partial,
        f16* __restrict__ z) {
    __shared__ float s_sum[64], s_sq[64];
    int tid = threadIdx.x;
    int wv = tid >> 6, lane = tid & 63;
    int quad = lane >> 4, n = lane & 15;
    int rowbase = blockIdx.x * 64 + wv * 16;
    int arow = rowbase + n;  // A-operand row m = lane&15

    if (STATS) {
        if (tid < 64) { s_sum[tid] = 0.f; s_sq[tid] = 0.f; }
        __syncthreads();
    }

    f4v acc0 = {0.f, 0.f, 0.f, 0.f};
    f4v acc1 = {0.f, 0.f, 0.f, 0.f};
    f4v acc2 = {0.f, 0.f, 0.f, 0.f};
    f4v acc3 = {0.f, 0.f, 0.f, 0.f};

#pragma unroll
    for (int ch = 0; ch < NCH; ++ch) {
        const ushort* sp = (ch == 0) ? s0 : (ch == 1) ? s1 : (ch == 2) ? s2
                         : (ch == 3) ? s3 : (ch == 4) ? s4 : s5;
        int st = (ch == 0) ? st0 : (ch == 1) ? st1 : (ch == 2) ? st2
               : (ch == 3) ? st3 : (ch == 4) ? st4 : st5;
        const ushort* wb = (ch < NCH1) ? (Wt1 + (size_t)ch * 2048)
                                       : (Wt2 + (size_t)(ch - NCH1) * 2048);
        s8v a = *(const s8v*)(sp + (size_t)arow * st + quad * 8);
        const ushort* wq = wb + lane * 8;
        s8v b0 = *(const s8v*)(wq + 0 * 512);
        s8v b1 = *(const s8v*)(wq + 1 * 512);
        s8v b2 = *(const s8v*)(wq + 2 * 512);
        s8v b3 = *(const s8v*)(wq + 3 * 512);
        acc0 = __builtin_amdgcn_mfma_f32_16x16x32_bf16(a, b0, acc0, 0, 0, 0);
        acc1 = __builtin_amdgcn_mfma_f32_16x16x32_bf16(a, b1, acc1, 0, 0, 0);
        acc2 = __builtin_amdgcn_mfma_f32_16x16x32_bf16(a, b2, acc2, 0, 0, 0);
        acc3 = __builtin_amdgcn_mfma_f32_16x16x32_bf16(a, b3, acc3, 0, 0, 0);
    }
    // C/D layout: col = lane&15, row = quad*4 + reg
    float fs[4] = {0.f, 0.f, 0.f, 0.f};
    float fq[4] = {0.f, 0.f, 0.f, 0.f};
#pragma unroll
    for (int r = 0; r < 4; ++r) {
        int orow = rowbase + quad * 4 + r;
        f16* zp = z + (size_t)orow * 64 + n;
        f16 w0, w1, w2, w3;
        if (INIT) {
            w0 = (f16)(bias[n]      + acc0[r]);
            w1 = (f16)(bias[16 + n] + acc1[r]);
            w2 = (f16)(bias[32 + n] + acc2[r]);
            w3 = (f16)(bias[48 + n] + acc3[r]);
        } else {
            w0 = (f16)((float)zp[0]  + acc0[r]);
            w1 = (f16)((float)zp[16] + acc1[r]);
            w2 = (f16)((float)zp[32] + acc2[r]);
            w3 = (f16)((float)zp[48] + acc3[r]);
        }
        zp[0] = w0; zp[16] = w1; zp[32] = w2; zp[48] = w3;
        if (STATS) {
            float v0 = (float)w0, v1 = (float)w1, v2 = (float)w2, v3 = (float)w3;
            fs[0] += v0; fq[0] += v0 * v0;
            fs[1] += v1; fq[1] += v1 * v1;
            fs[2] += v2; fq[2] += v2 * v2;
            fs[3] += v3; fq[3] += v3 * v3;
        }
    }
    if (STATS) {
#pragma unroll
        for (int k = 0; k < 4; ++k) {
            atomicAdd(&s_sum[k * 16 + n], fs[k]);
            atomicAdd(&s_sq[k * 16 + n], fq[k]);
        }
        __syncthreads();
        // contention-free per-block partial (coalesced 512B store)
        if (tid < 64)  partial[(size_t)blockIdx.x * 128 + tid] = s_sum[tid];
        else if (tid < 128) partial[(size_t)blockIdx.x * 128 + tid] = s_sq[tid - 64];
    }
}

// reduce partial[6250][128] -> stats[128] doubles (one block per slot)
__global__ __launch_bounds__(256) void stats_reduce_kernel(
        const float* __restrict__ partial, double* __restrict__ stats) {
    __shared__ double sd[256];
    int slot = blockIdx.x;
    int t = threadIdx.x;
    double acc = 0.0;
    for (int j = t; j < MF_BLOCKS_C; j += 256)
        acc += (double)partial[(size_t)j * 128 + slot];
    sd[t] = acc;
    __syncthreads();
    for (int off = 128; off > 0; off >>= 1) {
        if (t < off) sd[t] += sd[t + off];
        __syncthreads();
    }
    if (t == 0) stats[slot] = sd[0];
}

// ---------------- BN / pool / MLP (vectorized) ----------------

// layer-0: h0bf = bf16(elu(bn(z)))
__global__ void bn_elu_bf16_kernel(const f16* __restrict__ z, const double* __restrict__ stats,
                                   const float* __restrict__ gamma, const float* __restrict__ beta,
                                   bf16* __restrict__ out) {
    __shared__ float scale_s[64], shift_s[64];
    int tid = threadIdx.x;
    if (tid < 64) {
        double mean = stats[tid] / (double)N_SIMP;
        double var = stats[64 + tid] / (double)N_SIMP - mean * mean;
        double sc = (double)gamma[tid] / sqrt(var + BN_EPS);
        scale_s[tid] = (float)sc;
        shift_s[tid] = (float)((double)beta[tid] - mean * sc);
    }
    __syncthreads();
    const h8v* z8 = (const h8v*)z;
    u8v* o8 = (u8v*)out;
    const int total8 = N_SIMP * HDIM / 8;
    int hb = (tid & 7) * 8;
    for (int i = blockIdx.x * 256 + tid; i < total8; i += (int)gridDim.x * 256) {
        h8v v = z8[i];
        u8v w;
#pragma unroll
        for (int c = 0; c < 8; ++c)
            w[c] = f2bf(elu_f((float)v[c] * scale_s[hb + c] + shift_s[hb + c]));
        o8[i] = w;
    }
}

// fused bn1 + elu + global max/mean pool: reads raw z, applies elu(bn(z)) inline.
// 8 lanes/row (h8v = 16B each), 32 rows in flight per 256-thread block.
__global__ void pool_bn_kernel(const f16* __restrict__ zbuf, const int* __restrict__ bidx,
                               const double* __restrict__ stats,
                               const float* __restrict__ gamma, const float* __restrict__ beta,
                               float* __restrict__ gbuf) {
    __shared__ float scale_s[64], shift_s[64];
    __shared__ float pmax[256 * 8], psum[256 * 8];
    int tid = threadIdx.x;
    if (tid < 64) {
        double mean = stats[tid] / (double)N_SIMP;
        double var = stats[64 + tid] / (double)N_SIMP - mean * mean;
        double sc = (double)gamma[tid] / sqrt(var + BN_EPS);
        scale_s[tid] = (float)sc;
        shift_s[tid] = (float)((double)beta[tid] - mean * sc);
    }
    __syncthreads();
    int g = blockIdx.x;
    int lo = 0, hi = N_SIMP;
    while (lo < hi) { int mid = (lo + hi) >> 1; if (bidx[mid] < g) lo = mid + 1; else hi = mid; }
    int start = lo;
    hi = N_SIMP;
    while (lo < hi) { int mid = (lo + hi) >> 1; if (bidx[mid] < g + 1) lo = mid + 1; else hi = mid; }
    int end = lo;
    int li = tid & 7;        // channel block: li*8 .. li*8+7
    int rr = tid >> 3;       // row offset 0..31
    const h8v* z8 = (const h8v*)zbuf;
    float mx[8], sm[8];
#pragma unroll
    for (int c = 0; c < 8; ++c) { mx[c] = -INFINITY; sm[c] = 0.f; }
    float sc8[8], sh8[8];
#pragma unroll
    for (int c = 0; c < 8; ++c) { sc8[c] = scale_s[li * 8 + c]; sh8[c] = shift_s[li * 8 + c]; }
    for (int i = start + rr; i < end; i += 32) {
        h8v v = z8[(size_t)i * 8 + li];
#pragma unroll
        for (int c = 0; c < 8; ++c) {
            float y = elu_f((float)v[c] * sc8[c] + sh8[c]);
            mx[c] = fmaxf(mx[c], y);
            sm[c] += y;
        }
    }
#pragma unroll
    for (int c = 0; c < 8; ++c) { pmax[tid * 8 + c] = mx[c]; psum[tid * 8 + c] = sm[c]; }
    __syncthreads();
    if (tid < 64) {
        int sel = tid >> 3, slot = tid & 7;   // li = sel, c = slot
        float m = -INFINITY, s = 0.f;
#pragma unroll 8
        for (int k = 0; k < 32; ++k) {
            int t = k * 8 + sel;
            m = fmaxf(m, pmax[t * 8 + slot]);
            s += psum[t * 8 + slot];
        }
        int cnt = end - start;
        float mean = s / fmaxf((float)cnt, 1.f);
        gbuf[g * 128 + tid] = elu_f(m);
        gbuf[g * 128 + 64 + tid] = elu_f(mean);
    }
}

__global__ void mlp_kernel(const float* __restrict__ gbuf, const float* __restrict__ W1,
                           const float* __restrict__ b1, const float* __restrict__ W2,
                           const float* __restrict__ b2, float* __restrict__ out) {
    __shared__ float gs[128];
    __shared__ float hs[64];
    int g = blockIdx.x, tid = threadIdx.x;
    gs[tid] = gbuf[g * 128 + tid];
    gs[64 + tid] = gbuf[g * 128 + 64 + tid];
    __syncthreads();
    float acc = b1[tid];
#pragma unroll
    for (int k = 0; k < 128; ++k) acc += gs[k] * W1[k * 64 + tid];
    hs[tid] = fmaxf(acc, 0.f);
    __syncthreads();
    if (tid < 8) {
        float o = b2[tid];
#pragma unroll
        for (int k = 0; k < 64; ++k) o += hs[k] * W2[k * 8 + tid];
        out[g * 8 + tid] = o;
    }
}

// ---------------- host side ----------------

extern "C" void kernel_launch(void* const* d_in, const int* in_sizes, int n_in,
                              void* d_out, int out_size, void* d_ws, size_t ws_size,
                              hipStream_t stream) {
    const float* x     = (const float*)d_in[0];
    const int*   li    = (const int*)d_in[1];
    const float* lv    = (const float*)d_in[2];
    const int*   ui    = (const int*)d_in[3];
    const float* uv    = (const float*)d_in[4];
    const int*   bidx  = (const int*)d_in[5];
    const float* l0_Wl = (const float*)d_in[6];
    const float* l0_bl = (const float*)d_in[7];
    const float* l0_Wu = (const float*)d_in[8];
    const float* l0_bu = (const float*)d_in[9];
    const float* l0_Wh = (const float*)d_in[10];
    const float* l0_bh = (const float*)d_in[11];
    const float* l1_Wl = (const float*)d_in[12];
    const float* l1_bl = (const float*)d_in[13];
    const float* l1_Wu = (const float*)d_in[14];
    const float* l1_bu = (const float*)d_in[15];
    const float* l1_Wh = (const float*)d_in[16];
    const float* l1_bh = (const float*)d_in[17];
    const float* bn0_g = (const float*)d_in[18];
    const float* bn0_b = (const float*)d_in[19];
    const float* bn1_g = (const float*)d_in[20];
    const float* bn1_b = (const float*)d_in[21];
    const float* mW1   = (const float*)d_in[22];
    const float* mb1   = (const float*)d_in[23];
    const float* mW2   = (const float*)d_in[24];
    const float* mb2   = (const float*)d_in[25];
    float* out = (float*)d_out;

    // ---- workspace layout (total ~250.2 MB <= 256 MiB) ----
    char* base = (char*)d_ws;
    f16*   z     = (f16*)base;                                    //  51,200,000
    bf16*  h0bf  = (bf16*)(base + 51200000ull);                   //  51,200,000
    bf16*  g1    = (bf16*)(base + 102400000ull);                  //  51,200,000
    bf16*  g2    = (bf16*)(base + 153600000ull);                  //  51,200,000
    int2*  edgeL = (int2*)(base + 204800000ull);                  //  19,200,000
    int2*  edgeU = (int2*)(base + 224000000ull);                  //  19,200,000
    int*   rpL   = (int*)(base + 243200000ull);                   //   1,600,032
    int*   rpU   = (int*)(base + 244800032ull);                   //   1,600,032
    double* stats = (double*)(base + 246404160ull);               //   1 KB
    float* cbias  = (float*)(base + 246405184ull);                //   256 B
    float* gbuf   = (float*)(base + 246405440ull);                //   262,144
    ushort* wt    = (ushort*)(base + 246667584ull);               //   86,016
    float* partial = (float*)(base + 246760000ull);               //   3,200,000 (tail)

    // CSR-build scratch aliases (regions dead during build):
    //  z region   : coarse 38.4 MB + basev 3.1 KB
    //  h0bf region: ccnt 1.83 MB + bofs 1.83 MB
    int2* coarse = (int2*)base;                                   // 38,404,096
    int*  basev  = (int*)(base + 38500000ull);                    // (NDIG+1)*4
    int*  ccnt   = (int*)(base + 51200000ull);                    // 1,833,008
    int*  bofsv  = (int*)(base + 53100000ull);                    // 1,833,008

    // layer-0 scratch: 6 slots of N*32 bf16 in g1/g2/h0bf regions
    bf16* xbf  = g1;                                 // g1 slot 0 (later cCU)
    bf16* cAL  = g1 + (size_t)N_SIMP * 32;           // g1 slot 1
    bf16* cBL  = g2;                                 // g2 slot 0
    bf16* cCL  = g2 + (size_t)N_SIMP * 32;           // g2 slot 1
    bf16* cAU  = h0bf;                               // h0 slot 0
    bf16* cBU  = h0bf + (size_t)N_SIMP * 32;         // h0 slot 1
    bf16* cCU  = g1;                                 // reuses xbf slot (xbf dead)

    // weight-fragment sub-buffers (ushort elements; 2048 ushorts per channel)
    ushort* wt_l0h = wt;            // 1 ch  (K=32)
    ushort* wt_l1h = wt + 2048;     // 2 ch  (K=64)
    ushort* wt_l0l = wt + 6144;     // 3 ch  (K=96)
    ushort* wt_l0u = wt + 12288;    // 3 ch  (K=96)
    ushort* wt_l1l = wt + 18432;    // 6 ch  (K=192)
    ushort* wt_l1u = wt + 30720;    // 6 ch  (K=192)

    const int SP32_BLOCKS = N_SIMP / 64;   // 6,250
    const int SP64_BLOCKS = N_SIMP / 32;   // 12,500
    const int MF_BLOCKS   = N_SIMP / 64;   // 6,250

    // ---- prep: weight transposes (one dispatch) + x->bf16 ----
    wtrans_all_kernel<<<168, 256, 0, stream>>>(l0_Wh, l1_Wh, l0_Wl, l0_Wu, l1_Wl, l1_Wu, wt);
    f32_to_bf16_kernel<<<N_SIMP * 32 / 4 / 256, 256, 0, stream>>>(x, xbf);

    // ---- CSR builds: in-LDS block sort + fragment-gather bucket sort ----
    p1_sort_kernel<<<P1_BLOCKS, P1_T, 0, stream>>>(li, lv, ui, uv, ccnt, bofsv, coarse);
    digit_total_kernel<<<(NDIG + 255) / 256, 256, 0, stream>>>(ccnt, basev);
    scan_base_kernel<<<1, 1024, 0, stream>>>(basev);
    p2_build_kernel<<<NDIG, P2_T, 0, stream>>>(coarse, ccnt, bofsv, basev,
                                               rpL, rpU, edgeL, edgeU);

    const ushort* xbfu = (const ushort*)xbf;
    const ushort* h0u  = (const ushort*)h0bf;
    const ushort* g1u  = (const ushort*)g1;
    const ushort* g2u  = (const ushort*)g2;

    // ---------------- layer 0 (F_IN=32 -> H=64) ----------------
    combine_bias_kernel<<<1, 64, 0, stream>>>(l0_bh, l0_bl, l0_bu, cbias);
    mfma_gemm_kernel<1, 1, true, false><<<MF_BLOCKS, 256, 0, stream>>>(
        xbfu, 32, nullptr, 0, nullptr, 0, nullptr, 0, nullptr, 0, nullptr, 0,
        wt_l0h, wt_l0h, cbias, nullptr, z);

    // lower chain
    spmm32_kernel<<<SP32_BLOCKS, 256, 0, stream>>>(rpL, edgeL, xbf, 32, cAL);
    spmm32_kernel<<<SP32_BLOCKS, 256, 0, stream>>>(rpL, edgeL, cAL, 32, cBL);
    spmm32_kernel<<<SP32_BLOCKS, 256, 0, stream>>>(rpL, edgeL, cBL, 32, cCL);
    // upper chain (cAU spmm reads xbf before cCU overwrites that slot)
    spmm32_kernel<<<SP32_BLOCKS, 256, 0, stream>>>(rpU, edgeU, xbf, 32, cAU);
    spmm32_kernel<<<SP32_BLOCKS, 256, 0, stream>>>(rpU, edgeU, cAU, 32, cBU);
    spmm32_kernel<<<SP32_BLOCKS, 256, 0, stream>>>(rpU, edgeU, cBU, 32, cCU);
    // single accumulate-GEMM over all 6 chain outputs, with fused BN0 partials
    mfma_gemm_kernel<6, 3, false, true><<<MF_BLOCKS, 256, 0, stream>>>(
        (const ushort*)cAL, 32, (const ushort*)cBL, 32, (const ushort*)cCL, 32,
        (const ushort*)cAU, 32, (const ushort*)cBU, 32, (const ushort*)cCU, 32,
        wt_l0l, wt_l0u, nullptr, partial, z);
    stats_reduce_kernel<<<128, 256, 0, stream>>>(partial, stats);

    bn_elu_bf16_kernel<<<1024, 256, 0, stream>>>(z, stats, bn0_g, bn0_b, h0bf);

    // ---------------- layer 1 (H=64 -> H=64), 64-wide chains ----------------
    combine_bias_kernel<<<1, 64, 0, stream>>>(l1_bh, l1_bl, l1_bu, cbias);

    // u1 = L h0 -> g1 ; u2 = L u1 -> g2
    spmm64_kernel<<<SP64_BLOCKS, 256, 0, stream>>>(rpL, edgeL, h0bf, g1);
    spmm64_kernel<<<SP64_BLOCKS, 256, 0, stream>>>(rpL, edgeL, g1, g2);
    // gemm A (INIT): h0 (wt_l1h ch 0-1), u1+u2 (wt_l1l ch 0-3), + bias
    mfma_gemm_kernel<6, 2, true, false><<<MF_BLOCKS, 256, 0, stream>>>(
        h0u, 64, h0u + 32, 64, g1u, 64, g1u + 32, 64, g2u, 64, g2u + 32, 64,
        wt_l1h, wt_l1l, cbias, nullptr, z);
    // u3 = L u2 -> g1 ; v1 = U h0 -> g2
    spmm64_kernel<<<SP64_BLOCKS, 256, 0, stream>>>(rpL, edgeL, g2, g1);
    spmm64_kernel<<<SP64_BLOCKS, 256, 0, stream>>>(rpU, edgeU, h0bf, g2);
    // gemm B: u3 (wt_l1l ch 4-5), v1 (wt_l1u ch 0-1)
    mfma_gemm_kernel<4, 2, false, false><<<MF_BLOCKS, 256, 0, stream>>>(
        g1u, 64, g1u + 32, 64, g2u, 64, g2u + 32, 64, nullptr, 0, nullptr, 0,
        wt_l1l + 4 * 2048, wt_l1u, nullptr, nullptr, z);
    // v2 = U v1 -> g1 ; v3 = U v2 -> g2
    spmm64_kernel<<<SP64_BLOCKS, 256, 0, stream>>>(rpU, edgeU, g2, g1);
    spmm64_kernel<<<SP64_BLOCKS, 256, 0, stream>>>(rpU, edgeU, g1, g2);
    // gemm C: v2+v3 (wt_l1u ch 2-5), with fused BN1 partials (z final here)
    mfma_gemm_kernel<4, 4, false, true><<<MF_BLOCKS, 256, 0, stream>>>(
        g1u, 64, g1u + 32, 64, g2u, 64, g2u + 32, 64, nullptr, 0, nullptr, 0,
        wt_l1u + 2 * 2048, wt_l1u + 2 * 2048, nullptr, partial, z);
    stats_reduce_kernel<<<128, 256, 0, stream>>>(partial, stats);

    // ---------------- fused bn1+elu+pool, then MLP ----------------
    pool_bn_kernel<<<G_NUM, 256, 0, stream>>>(z, bidx, stats, bn1_g, bn1_b, gbuf);
    mlp_kernel<<<G_NUM, 64, 0, stream>>>(gbuf, mW1, mb1, mW2, mb2, out);
}